// Round 9
// baseline (611.494 us; speedup 1.0000x reference)
//
#include <hip/hip_runtime.h>
#include <hip/hip_bf16.h>

#define NN 100000
#define EE 1250000
#define DD 64
#define GG 256
#define BN_NODES 16
#define NBUCK (NN / BN_NODES)   // 6250 (exact)
#define NSLICE 8
#define BUCK_PER_SLICE ((NBUCK + NSLICE - 1) / NSLICE)  // 782

static __device__ __forceinline__ float relu_f(float x) { return fmaxf(x, 0.0f); }

static __device__ __forceinline__ float b2f(ushort u) {
    return __uint_as_float(((unsigned int)u) << 16);
}
static __device__ __forceinline__ ushort f2b(float f) {
    __hip_bfloat16 h = __float2bfloat16(f);  // RNE
    return *(ushort*)&h;
}

// ---------------- stage 1: coarse bucket sort of edges by dst>>4 ----------------

__global__ void bhist_kernel(const int* __restrict__ dst, int* __restrict__ bhist, int E) {
    int e = blockIdx.x * blockDim.x + threadIdx.x;
    if (e < E) atomicAdd(&bhist[dst[e] >> 4], 1);
}

// single-block exclusive scan over NBUCK=6250 (7 chunks of 1024)
__global__ __launch_bounds__(1024) void bscan_kernel(
    const int* __restrict__ bhist, int* __restrict__ boffs, int* __restrict__ bcursor) {
    __shared__ int tmp[1024];
    __shared__ int carry;
    int t = threadIdx.x;
    if (t == 0) carry = 0;
    __syncthreads();
    for (int base = 0; base < NBUCK; base += 1024) {
        int v = (base + t < NBUCK) ? bhist[base + t] : 0;
        tmp[t] = v;
        __syncthreads();
        for (int d = 1; d < 1024; d <<= 1) {
            int u = (t >= d) ? tmp[t - d] : 0;
            __syncthreads();
            tmp[t] += u;
            __syncthreads();
        }
        int excl = tmp[t] - v + carry;
        if (base + t < NBUCK) { boffs[base + t] = excl; bcursor[base + t] = excl; }
        __syncthreads();
        if (t == 1023) carry += tmp[1023];
        __syncthreads();
    }
    if (t == 0) boffs[NBUCK] = carry;
}

// XCD-sliced scatter: slice s (= blockIdx&7, round-robin XCD heuristic) handles
// only buckets [s*782,(s+1)*782) -> each XCD writes a contiguous 1/8 of epack,
// killing the cross-XCD line ping-pong (round-8: 64.6MB writeback for 5MB data).
__global__ __launch_bounds__(256) void bscatter_kernel(
    const int* __restrict__ ei, int* __restrict__ bcursor,
    int* __restrict__ epack, int E) {
    int slice = blockIdx.x & (NSLICE - 1);
    int chunk = blockIdx.x >> 3;
    int nchunk = gridDim.x >> 3;
    int b0 = slice * BUCK_PER_SLICE;
    int b1 = min(NBUCK, b0 + BUCK_PER_SLICE);
    for (int e = chunk * blockDim.x + threadIdx.x; e < E; e += nchunk * blockDim.x) {
        int d = ei[E + e];
        int b = d >> 4;
        if (b >= b0 && b < b1) {
            int s = ei[e];
            int pos = atomicAdd(&bcursor[b], 1);
            epack[pos] = s | ((d & (BN_NODES - 1)) << 20);
        }
    }
}

// ---------------- stage 2: refine buckets into exact CSR (contiguous writes) ----
__global__ __launch_bounds__(256) void refine_kernel(
    const int* __restrict__ epack, const int* __restrict__ boffs,
    int* __restrict__ srcs, int* __restrict__ off) {
    __shared__ int cnt[4][BN_NODES];
    __shared__ int pre[4][BN_NODES];
    int wave = threadIdx.x >> 6, lane = threadIdx.x & 63;
    int b = blockIdx.x * 4 + wave;
    bool active = (b < NBUCK);
    int j0 = 0, j1 = 0;
    if (active) { j0 = boffs[b]; j1 = boffs[b + 1]; }
    if (lane < BN_NODES) cnt[wave][lane] = 0;
    __syncthreads();
    if (active) {
        for (int j = j0 + lane; j < j1; j += 64)
            atomicAdd(&cnt[wave][epack[j] >> 20], 1);
    }
    __syncthreads();
    if (active && lane == 0) {
        int run = 0;
        for (int r = 0; r < BN_NODES; r++) { pre[wave][r] = run; run += cnt[wave][r]; }
    }
    __syncthreads();
    if (active && lane < BN_NODES) {
        off[b * BN_NODES + lane] = j0 + pre[wave][lane];
        cnt[wave][lane] = pre[wave][lane];              // reuse as cursor
        if (b == NBUCK - 1 && lane == 0) off[NN] = j1;
    }
    __syncthreads();
    if (active) {
        for (int j = j0 + lane; j < j1; j += 64) {
            int p = epack[j];
            int pos = j0 + atomicAdd(&cnt[wave][p >> 20], 1);
            srcs[pos] = p & 0xFFFFF;
        }
    }
}

// graph boundaries from sorted batch
__global__ void bounds_kernel(const int* __restrict__ batch, int* __restrict__ gstart, int n) {
    int i = blockIdx.x * blockDim.x + threadIdx.x;
    if (i >= n) return;
    int b = batch[i];
    int prev = (i == 0) ? -1 : batch[i - 1];
    for (int g = prev + 1; g <= b; g++) gstart[g] = i;
    if (i == n - 1) {
        for (int g = b + 1; g <= GG; g++) gstart[g] = n;
    }
}

// fp32 -> bf16 cast of x (once)
__global__ __launch_bounds__(256) void cast_kernel(const float* __restrict__ x,
                                                   ushort* __restrict__ xb) {
    size_t i = ((size_t)blockIdx.x * blockDim.x + threadIdx.x) * 4;
    if (i >= (size_t)NN * DD) return;
    float4 v = *(const float4*)(x + i);
    ushort4 r;
    r.x = f2b(v.x); r.y = f2b(v.y); r.z = f2b(v.z); r.w = f2b(v.w);
    *(ushort4*)(xb + i) = r;
}

// ---------------- aggregation: wave per node, bf16 gather, 8-deep unroll ------
__global__ __launch_bounds__(256) void agg_kernel(
    const ushort* __restrict__ xb, float* __restrict__ u,
    const int* __restrict__ off, const int* __restrict__ srcs, int n) {
    int node = blockIdx.x * 4 + (threadIdx.x >> 6);
    int lane = threadIdx.x & 63;
    if (node >= n) return;
    int o = off[node];
    int oe = off[node + 1];
    float a0 = b2f(xb[(size_t)node * DD + lane]);   // self
    float a1 = 0.0f, a2 = 0.0f, a3 = 0.0f, a4 = 0.0f, a5 = 0.0f, a6 = 0.0f, a7 = 0.0f;
    int j = o;
    for (; j + 8 <= oe; j += 8) {
        int s0 = srcs[j + 0], s1 = srcs[j + 1], s2 = srcs[j + 2], s3 = srcs[j + 3];
        int s4 = srcs[j + 4], s5 = srcs[j + 5], s6 = srcs[j + 6], s7 = srcs[j + 7];
        ushort v0 = xb[(size_t)s0 * DD + lane];
        ushort v1 = xb[(size_t)s1 * DD + lane];
        ushort v2 = xb[(size_t)s2 * DD + lane];
        ushort v3 = xb[(size_t)s3 * DD + lane];
        ushort v4 = xb[(size_t)s4 * DD + lane];
        ushort v5 = xb[(size_t)s5 * DD + lane];
        ushort v6 = xb[(size_t)s6 * DD + lane];
        ushort v7 = xb[(size_t)s7 * DD + lane];
        a0 += b2f(v0); a1 += b2f(v1); a2 += b2f(v2); a3 += b2f(v3);
        a4 += b2f(v4); a5 += b2f(v5); a6 += b2f(v6); a7 += b2f(v7);
    }
    for (; j + 4 <= oe; j += 4) {
        int s0 = srcs[j + 0], s1 = srcs[j + 1], s2 = srcs[j + 2], s3 = srcs[j + 3];
        ushort v0 = xb[(size_t)s0 * DD + lane];
        ushort v1 = xb[(size_t)s1 * DD + lane];
        ushort v2 = xb[(size_t)s2 * DD + lane];
        ushort v3 = xb[(size_t)s3 * DD + lane];
        a0 += b2f(v0); a1 += b2f(v1); a2 += b2f(v2); a3 += b2f(v3);
    }
    for (; j < oe; j++) a0 += b2f(xb[(size_t)srcs[j] * DD + lane]);
    u[(size_t)node * DD + lane] = ((a0 + a1) + (a2 + a3)) + ((a4 + a5) + (a6 + a7));
}

// ---------------- per-layer: fused MLP + outer ReLU (+ BN) -----------------
// ILP-restructured (round 8: VALUBusy 23%, 1.5 waves/SIMD grid-limited):
// j unrolled x2 (two independent a-columns + weight prefetch overlap),
// k-sum split into 4 partials (breaks the 64-deep dependent FMA chain).
template <bool HAS_BN, bool OUT_BF16>
__global__ __launch_bounds__(256) void mlp_kernel(
    const float* __restrict__ u, void* __restrict__ hout,
    const float* __restrict__ wa, const float* __restrict__ ba,
    const float* __restrict__ wb, const float* __restrict__ bb,
    const float* __restrict__ bng, const float* __restrict__ bnb,
    const float* __restrict__ bnm, const float* __restrict__ bnv, int n) {
    int i = blockIdx.x * blockDim.x + threadIdx.x;
    if (i >= n) return;

    float uu[DD];
    const float4* up = (const float4*)(u + (size_t)i * DD);
#pragma unroll
    for (int q = 0; q < DD / 4; q++) {
        float4 v = up[q];
        uu[4 * q + 0] = v.x; uu[4 * q + 1] = v.y;
        uu[4 * q + 2] = v.z; uu[4 * q + 3] = v.w;
    }

    float acc[DD];
#pragma unroll
    for (int o = 0; o < DD; o++) acc[o] = bb[o];

#pragma unroll 1
    for (int j = 0; j < DD; j += 2) {   // j wave-uniform -> weight loads stay scalar
        float q00 = 0.0f, q01 = 0.0f, q02 = 0.0f, q03 = 0.0f;
        float q10 = 0.0f, q11 = 0.0f, q12 = 0.0f, q13 = 0.0f;
#pragma unroll
        for (int k = 0; k < 16; k++) {
            q00 = fmaf(uu[k],      wa[(k)*DD + j],          q00);
            q01 = fmaf(uu[16 + k], wa[(16 + k) * DD + j],   q01);
            q02 = fmaf(uu[32 + k], wa[(32 + k) * DD + j],   q02);
            q03 = fmaf(uu[48 + k], wa[(48 + k) * DD + j],   q03);
            q10 = fmaf(uu[k],      wa[(k)*DD + j + 1],        q10);
            q11 = fmaf(uu[16 + k], wa[(16 + k) * DD + j + 1], q11);
            q12 = fmaf(uu[32 + k], wa[(32 + k) * DD + j + 1], q12);
            q13 = fmaf(uu[48 + k], wa[(48 + k) * DD + j + 1], q13);
        }
        float a0 = relu_f(ba[j]     + ((q00 + q01) + (q02 + q03)));
        float a1 = relu_f(ba[j + 1] + ((q10 + q11) + (q12 + q13)));
#pragma unroll
        for (int o = 0; o < DD; o++)
            acc[o] = fmaf(a1, wb[(j + 1) * DD + o], fmaf(a0, wb[j * DD + o], acc[o]));
    }

#pragma unroll
    for (int q = 0; q < DD / 4; q++) {
        float v[4];
#pragma unroll
        for (int c = 0; c < 4; c++) {
            int o = 4 * q + c;
            float t = relu_f(acc[o]);
            if (HAS_BN) {
                float sc = bng[o] * rsqrtf(bnv[o] + 1e-5f);
                float sh = bnb[o] - bnm[o] * sc;
                t = fmaf(t, sc, sh);
            }
            v[c] = t;
        }
        if (OUT_BF16) {
            ushort4 r;
            r.x = f2b(v[0]); r.y = f2b(v[1]); r.z = f2b(v[2]); r.w = f2b(v[3]);
            ((ushort4*)((ushort*)hout + (size_t)i * DD))[q] = r;
        } else {
            float4 r; r.x = v[0]; r.y = v[1]; r.z = v[2]; r.w = v[3];
            ((float4*)((float*)hout + (size_t)i * DD))[q] = r;
        }
    }
}

// ---------------- pooling: one block per graph, zero atomics ----------------
__global__ __launch_bounds__(256) void pool_kernel(
    const float* __restrict__ h, const int* __restrict__ gstart,
    float* __restrict__ pmean, float* __restrict__ pmax) {
    __shared__ float ssum[4][DD];
    __shared__ float smax[4][DD];
    int g = blockIdx.x;
    int lane = threadIdx.x & 63;
    int wave = threadIdx.x >> 6;
    int s = gstart[g], e = gstart[g + 1];
    float sum = 0.0f, mx = 0.0f;  // layer-2 out is post-ReLU >= 0; 0 == empty-graph guard
    for (int i = s + wave; i < e; i += 4) {
        float v = h[(size_t)i * DD + lane];
        sum += v;
        mx = fmaxf(mx, v);
    }
    ssum[wave][lane] = sum;
    smax[wave][lane] = mx;
    __syncthreads();
    if (wave == 0) {
        sum = ssum[0][lane] + ssum[1][lane] + ssum[2][lane] + ssum[3][lane];
        mx = fmaxf(fmaxf(smax[0][lane], smax[1][lane]),
                   fmaxf(smax[2][lane], smax[3][lane]));
        float cnt = fmaxf((float)(e - s), 1.0f);
        pmean[g * DD + lane] = sum / cnt;
        pmax[g * DD + lane] = mx;
    }
}

// ---------------- head: MLP + log_softmax, one 64-thread block per graph ----
__global__ __launch_bounds__(64) void head_kernel(
    const float* __restrict__ pmean, const float* __restrict__ pmax,
    const float* __restrict__ wp1, const float* __restrict__ bp1,
    const float* __restrict__ wp2, const float* __restrict__ bp2,
    float* __restrict__ out) {
    __shared__ float gx[2 * DD];
    int g = blockIdx.x;
    int lane = threadIdx.x;
    gx[lane] = pmean[g * DD + lane];
    gx[DD + lane] = pmax[g * DD + lane];
    __syncthreads();
    float t = bp1[lane];
    for (int k = 0; k < 2 * DD; k++) t = fmaf(gx[k], wp1[k * DD + lane], t);
    float p0 = t * wp2[lane * 2 + 0];
    float p1 = t * wp2[lane * 2 + 1];
    for (int o = 32; o > 0; o >>= 1) {
        p0 += __shfl_down(p0, o);
        p1 += __shfl_down(p1, o);
    }
    if (lane == 0) {
        p0 += bp2[0];
        p1 += bp2[1];
        float m = fmaxf(p0, p1);
        float lse = m + logf(expf(p0 - m) + expf(p1 - m));
        out[g * 2 + 0] = p0 - lse;
        out[g * 2 + 1] = p1 - lse;
    }
}

// ---------------- launch ----------------
extern "C" void kernel_launch(void* const* d_in, const int* in_sizes, int n_in,
                              void* d_out, int out_size, void* d_ws, size_t ws_size,
                              hipStream_t stream) {
    const float* x     = (const float*)d_in[0];
    const int*   ei    = (const int*)d_in[1];
    const int*   batch = (const int*)d_in[2];
    const float* w0a = (const float*)d_in[3];  const float* b0a = (const float*)d_in[4];
    const float* w0b = (const float*)d_in[5];  const float* b0b = (const float*)d_in[6];
    const float* w1a = (const float*)d_in[7];  const float* b1a = (const float*)d_in[8];
    const float* w1b = (const float*)d_in[9];  const float* b1b = (const float*)d_in[10];
    const float* w2a = (const float*)d_in[11]; const float* b2a = (const float*)d_in[12];
    const float* w2b = (const float*)d_in[13]; const float* b2b = (const float*)d_in[14];
    const float* bn0g = (const float*)d_in[15]; const float* bn0b = (const float*)d_in[16];
    const float* bn0m = (const float*)d_in[17]; const float* bn0v = (const float*)d_in[18];
    const float* bn1g = (const float*)d_in[19]; const float* bn1b = (const float*)d_in[20];
    const float* bn1m = (const float*)d_in[21]; const float* bn1v = (const float*)d_in[22];
    const float* wp1 = (const float*)d_in[23]; const float* bp1 = (const float*)d_in[24];
    const float* wp2 = (const float*)d_in[25]; const float* bp2 = (const float*)d_in[26];
    float* out = (float*)d_out;

    char* p = (char*)d_ws;
    auto take = [&](size_t bytes) {
        char* r = p;
        p += (bytes + 255) & ~(size_t)255;
        return r;
    };
    int* bhist   = (int*)take(NBUCK * sizeof(int));
    int* boffs   = (int*)take((NBUCK + 1) * sizeof(int));
    int* bcursor = (int*)take(NBUCK * sizeof(int));
    int* epack   = (int*)take(EE * sizeof(int));
    int* srcs    = (int*)take(EE * sizeof(int));
    int* off     = (int*)take((NN + 1) * sizeof(int));
    int* gstart  = (int*)take((GG + 1) * sizeof(int));
    ushort* xb   = (ushort*)take((size_t)NN * DD * sizeof(ushort));
    float* bufU  = (float*)take((size_t)NN * DD * sizeof(float));
    ushort* hA   = (ushort*)take((size_t)NN * DD * sizeof(ushort));
    ushort* hB   = (ushort*)take((size_t)NN * DD * sizeof(ushort));
    float* pmean = (float*)take(GG * DD * sizeof(float));
    float* pmax  = (float*)take(GG * DD * sizeof(float));

    // two-stage CSR build + graph bounds + x cast
    hipMemsetAsync(bhist, 0, NBUCK * sizeof(int), stream);
    bhist_kernel<<<(EE + 255) / 256, 256, 0, stream>>>(ei + EE, bhist, EE);
    bscan_kernel<<<1, 1024, 0, stream>>>(bhist, boffs, bcursor);
    bscatter_kernel<<<2048, 256, 0, stream>>>(ei, bcursor, epack, EE);
    refine_kernel<<<(NBUCK + 3) / 4, 256, 0, stream>>>(epack, boffs, srcs, off);
    bounds_kernel<<<(NN + 255) / 256, 256, 0, stream>>>(batch, gstart, NN);
    cast_kernel<<<(NN * DD / 4 + 255) / 256, 256, 0, stream>>>(x, xb);

    int agg_grid = (NN + 3) / 4;
    int mlp_grid = (NN + 255) / 256;

    // layer 0
    agg_kernel<<<agg_grid, 256, 0, stream>>>(xb, bufU, off, srcs, NN);
    mlp_kernel<true, true><<<mlp_grid, 256, 0, stream>>>(bufU, hA, w0a, b0a, w0b, b0b,
                                                         bn0g, bn0b, bn0m, bn0v, NN);
    // layer 1
    agg_kernel<<<agg_grid, 256, 0, stream>>>(hA, bufU, off, srcs, NN);
    mlp_kernel<true, true><<<mlp_grid, 256, 0, stream>>>(bufU, hB, w1a, b1a, w1b, b1b,
                                                         bn1g, bn1b, bn1m, bn1v, NN);
    // layer 2 (fp32 out, in-place on bufU: each thread reads its row before writing)
    agg_kernel<<<agg_grid, 256, 0, stream>>>(hB, bufU, off, srcs, NN);
    mlp_kernel<false, false><<<mlp_grid, 256, 0, stream>>>(bufU, bufU, w2a, b2a, w2b, b2b,
                                                           nullptr, nullptr, nullptr, nullptr, NN);

    // pooling (fp32 in, no atomics) + head
    pool_kernel<<<GG, 256, 0, stream>>>(bufU, gstart, pmean, pmax);
    head_kernel<<<GG, 64, 0, stream>>>(pmean, pmax, wp1, bp1, wp2, bp2, out);
}

// Round 10
// 415.020 us; speedup vs baseline: 1.4734x; 1.4734x over previous
//
#include <hip/hip_runtime.h>
#include <hip/hip_bf16.h>

#define NN 100000
#define EE 1250000
#define DD 64
#define GG 256
#define BN_NODES 16
#define NBUCK (NN / BN_NODES)   // 6250 (exact)

static __device__ __forceinline__ float relu_f(float x) { return fmaxf(x, 0.0f); }

static __device__ __forceinline__ float b2f(ushort u) {
    return __uint_as_float(((unsigned int)u) << 16);
}
static __device__ __forceinline__ ushort f2b(float f) {
    __hip_bfloat16 h = __float2bfloat16(f);  // RNE
    return *(ushort*)&h;
}

// ---------------- stage 1: coarse bucket sort of edges by dst>>4 ----------------

__global__ void bhist_kernel(const int* __restrict__ dst, int* __restrict__ bhist, int E) {
    int e = blockIdx.x * blockDim.x + threadIdx.x;
    if (e < E) atomicAdd(&bhist[dst[e] >> 4], 1);
}

// single-block exclusive scan over NBUCK=6250 (7 chunks of 1024)
__global__ __launch_bounds__(1024) void bscan_kernel(
    const int* __restrict__ bhist, int* __restrict__ boffs, int* __restrict__ bcursor) {
    __shared__ int tmp[1024];
    __shared__ int carry;
    int t = threadIdx.x;
    if (t == 0) carry = 0;
    __syncthreads();
    for (int base = 0; base < NBUCK; base += 1024) {
        int v = (base + t < NBUCK) ? bhist[base + t] : 0;
        tmp[t] = v;
        __syncthreads();
        for (int d = 1; d < 1024; d <<= 1) {
            int u = (t >= d) ? tmp[t - d] : 0;
            __syncthreads();
            tmp[t] += u;
            __syncthreads();
        }
        int excl = tmp[t] - v + carry;
        if (base + t < NBUCK) { boffs[base + t] = excl; bcursor[base + t] = excl; }
        __syncthreads();
        if (t == 1023) carry += tmp[1023];
        __syncthreads();
    }
    if (t == 0) boffs[NBUCK] = carry;
}

// simple scatter (round-8 proven; round-9 XCD-sliced variant regressed 63->104us)
__global__ void bscatter_kernel(const int* __restrict__ ei, int* __restrict__ bcursor,
                                int* __restrict__ epack, int E) {
    int e = blockIdx.x * blockDim.x + threadIdx.x;
    if (e < E) {
        int s = ei[e];          // src
        int d = ei[E + e];      // dst
        int pos = atomicAdd(&bcursor[d >> 4], 1);
        epack[pos] = s | ((d & (BN_NODES - 1)) << 20);
    }
}

// ---------------- stage 2: refine buckets into exact CSR (contiguous writes) ----
__global__ __launch_bounds__(256) void refine_kernel(
    const int* __restrict__ epack, const int* __restrict__ boffs,
    int* __restrict__ srcs, int* __restrict__ off) {
    __shared__ int cnt[4][BN_NODES];
    __shared__ int pre[4][BN_NODES];
    int wave = threadIdx.x >> 6, lane = threadIdx.x & 63;
    int b = blockIdx.x * 4 + wave;
    bool active = (b < NBUCK);
    int j0 = 0, j1 = 0;
    if (active) { j0 = boffs[b]; j1 = boffs[b + 1]; }
    if (lane < BN_NODES) cnt[wave][lane] = 0;
    __syncthreads();
    if (active) {
        for (int j = j0 + lane; j < j1; j += 64)
            atomicAdd(&cnt[wave][epack[j] >> 20], 1);
    }
    __syncthreads();
    if (active && lane == 0) {
        int run = 0;
        for (int r = 0; r < BN_NODES; r++) { pre[wave][r] = run; run += cnt[wave][r]; }
    }
    __syncthreads();
    if (active && lane < BN_NODES) {
        off[b * BN_NODES + lane] = j0 + pre[wave][lane];
        cnt[wave][lane] = pre[wave][lane];              // reuse as cursor
        if (b == NBUCK - 1 && lane == 0) off[NN] = j1;
    }
    __syncthreads();
    if (active) {
        for (int j = j0 + lane; j < j1; j += 64) {
            int p = epack[j];
            int pos = j0 + atomicAdd(&cnt[wave][p >> 20], 1);
            srcs[pos] = p & 0xFFFFF;
        }
    }
}

// graph boundaries from sorted batch
__global__ void bounds_kernel(const int* __restrict__ batch, int* __restrict__ gstart, int n) {
    int i = blockIdx.x * blockDim.x + threadIdx.x;
    if (i >= n) return;
    int b = batch[i];
    int prev = (i == 0) ? -1 : batch[i - 1];
    for (int g = prev + 1; g <= b; g++) gstart[g] = i;
    if (i == n - 1) {
        for (int g = b + 1; g <= GG; g++) gstart[g] = n;
    }
}

// fp32 -> bf16 cast of x (once)
__global__ __launch_bounds__(256) void cast_kernel(const float* __restrict__ x,
                                                   ushort* __restrict__ xb) {
    size_t i = ((size_t)blockIdx.x * blockDim.x + threadIdx.x) * 4;
    if (i >= (size_t)NN * DD) return;
    float4 v = *(const float4*)(x + i);
    ushort4 r;
    r.x = f2b(v.x); r.y = f2b(v.y); r.z = f2b(v.z); r.w = f2b(v.w);
    *(ushort4*)(xb + i) = r;
}

// ---------------- aggregation: wave per node, bf16 gather, 8-deep unroll ------
__global__ __launch_bounds__(256) void agg_kernel(
    const ushort* __restrict__ xb, float* __restrict__ u,
    const int* __restrict__ off, const int* __restrict__ srcs, int n) {
    int node = blockIdx.x * 4 + (threadIdx.x >> 6);
    int lane = threadIdx.x & 63;
    if (node >= n) return;
    int o = off[node];
    int oe = off[node + 1];
    float a0 = b2f(xb[(size_t)node * DD + lane]);   // self
    float a1 = 0.0f, a2 = 0.0f, a3 = 0.0f, a4 = 0.0f, a5 = 0.0f, a6 = 0.0f, a7 = 0.0f;
    int j = o;
    for (; j + 8 <= oe; j += 8) {
        int s0 = srcs[j + 0], s1 = srcs[j + 1], s2 = srcs[j + 2], s3 = srcs[j + 3];
        int s4 = srcs[j + 4], s5 = srcs[j + 5], s6 = srcs[j + 6], s7 = srcs[j + 7];
        ushort v0 = xb[(size_t)s0 * DD + lane];
        ushort v1 = xb[(size_t)s1 * DD + lane];
        ushort v2 = xb[(size_t)s2 * DD + lane];
        ushort v3 = xb[(size_t)s3 * DD + lane];
        ushort v4 = xb[(size_t)s4 * DD + lane];
        ushort v5 = xb[(size_t)s5 * DD + lane];
        ushort v6 = xb[(size_t)s6 * DD + lane];
        ushort v7 = xb[(size_t)s7 * DD + lane];
        a0 += b2f(v0); a1 += b2f(v1); a2 += b2f(v2); a3 += b2f(v3);
        a4 += b2f(v4); a5 += b2f(v5); a6 += b2f(v6); a7 += b2f(v7);
    }
    for (; j + 4 <= oe; j += 4) {
        int s0 = srcs[j + 0], s1 = srcs[j + 1], s2 = srcs[j + 2], s3 = srcs[j + 3];
        ushort v0 = xb[(size_t)s0 * DD + lane];
        ushort v1 = xb[(size_t)s1 * DD + lane];
        ushort v2 = xb[(size_t)s2 * DD + lane];
        ushort v3 = xb[(size_t)s3 * DD + lane];
        a0 += b2f(v0); a1 += b2f(v1); a2 += b2f(v2); a3 += b2f(v3);
    }
    for (; j < oe; j++) a0 += b2f(xb[(size_t)srcs[j] * DD + lane]);
    u[(size_t)node * DD + lane] = ((a0 + a1) + (a2 + a3)) + ((a4 + a5) + (a6 + a7));
}

// ---------------- per-layer: block-tiled fp32 GEMM MLP ---------------------
// Round-8 evidence: thread-per-node mlp spills (VGPR=68 for 128 live floats,
// VALUBusy 23%). Tiled version: block = 64 nodes, 16x16 threads x (4x4 tile),
// A^T + W staged in LDS (33KB), acc[4][4] in regs -> no spills.
template <bool HAS_BN, bool OUT_BF16>
__global__ __launch_bounds__(256) void mlp_kernel(
    const float* __restrict__ u, void* __restrict__ hout,
    const float* __restrict__ wa, const float* __restrict__ ba,
    const float* __restrict__ wb, const float* __restrict__ bb,
    const float* __restrict__ bng, const float* __restrict__ bnb,
    const float* __restrict__ bnm, const float* __restrict__ bnv, int n) {
    __shared__ float At[DD][68];   // A^T: At[k][i], 68-pad keeps rows 16B-aligned
    __shared__ float Wt[DD * DD];  // W[k][j] row-major
    int t = threadIdx.x;
    int r0 = blockIdx.x * DD;
    int tx = t & 15, ty = t >> 4;
    int i0 = tx * 4, j0 = ty * 4;

    // ---- stage A^T (thread t: row r0+t/4, 16 cols starting (t&3)*16) ----
    {
        int ii = t >> 2;
        int cb = (t & 3) * 16;
        int row = r0 + ii;
        if (row < n) {
            const float4* ur = (const float4*)(u + (size_t)row * DD + cb);
            float4 v0 = ur[0], v1 = ur[1], v2 = ur[2], v3 = ur[3];
            At[cb + 0][ii] = v0.x;  At[cb + 1][ii] = v0.y;
            At[cb + 2][ii] = v0.z;  At[cb + 3][ii] = v0.w;
            At[cb + 4][ii] = v1.x;  At[cb + 5][ii] = v1.y;
            At[cb + 6][ii] = v1.z;  At[cb + 7][ii] = v1.w;
            At[cb + 8][ii] = v2.x;  At[cb + 9][ii] = v2.y;
            At[cb + 10][ii] = v2.z; At[cb + 11][ii] = v2.w;
            At[cb + 12][ii] = v3.x; At[cb + 13][ii] = v3.y;
            At[cb + 14][ii] = v3.z; At[cb + 15][ii] = v3.w;
        } else {
#pragma unroll
            for (int q = 0; q < 16; q++) At[cb + q][ii] = 0.0f;
        }
        // stage Wa (canonical contiguous float4 copy)
#pragma unroll
        for (int rep = 0; rep < 4; rep++) {
            int idx = rep * 1024 + t * 4;
            *(float4*)&Wt[idx] = *(const float4*)&wa[idx];
        }
    }
    __syncthreads();

    // ---- GEMM1: z1 = A @ Wa ----
    float acc[4][4];
#pragma unroll
    for (int a = 0; a < 4; a++)
#pragma unroll
        for (int b = 0; b < 4; b++) acc[a][b] = 0.0f;
#pragma unroll 4
    for (int k = 0; k < DD; k++) {
        float4 av = *(const float4*)&At[k][i0];
        float4 wv = *(const float4*)&Wt[k * DD + j0];
        float aa[4] = {av.x, av.y, av.z, av.w};
        float ww[4] = {wv.x, wv.y, wv.z, wv.w};
#pragma unroll
        for (int di = 0; di < 4; di++)
#pragma unroll
            for (int dj = 0; dj < 4; dj++)
                acc[di][dj] = fmaf(aa[di], ww[dj], acc[di][dj]);
    }
    float4 ba4 = *(const float4*)&ba[j0];
    float bav[4] = {ba4.x, ba4.y, ba4.z, ba4.w};
    __syncthreads();   // all At/Wt reads done

    // ---- write z1^T into At; stage Wb ----
#pragma unroll
    for (int dj = 0; dj < 4; dj++) {
        float4 w;
        w.x = relu_f(acc[0][dj] + bav[dj]);
        w.y = relu_f(acc[1][dj] + bav[dj]);
        w.z = relu_f(acc[2][dj] + bav[dj]);
        w.w = relu_f(acc[3][dj] + bav[dj]);
        *(float4*)&At[j0 + dj][i0] = w;
    }
#pragma unroll
    for (int rep = 0; rep < 4; rep++) {
        int idx = rep * 1024 + t * 4;
        *(float4*)&Wt[idx] = *(const float4*)&wb[idx];
    }
    __syncthreads();

    // ---- GEMM2: z2 = z1 @ Wb ----
    float acc2[4][4];
#pragma unroll
    for (int a = 0; a < 4; a++)
#pragma unroll
        for (int b = 0; b < 4; b++) acc2[a][b] = 0.0f;
#pragma unroll 4
    for (int k = 0; k < DD; k++) {
        float4 av = *(const float4*)&At[k][i0];
        float4 wv = *(const float4*)&Wt[k * DD + j0];
        float aa[4] = {av.x, av.y, av.z, av.w};
        float ww[4] = {wv.x, wv.y, wv.z, wv.w};
#pragma unroll
        for (int di = 0; di < 4; di++)
#pragma unroll
            for (int dj = 0; dj < 4; dj++)
                acc2[di][dj] = fmaf(aa[di], ww[dj], acc2[di][dj]);
    }

    // ---- epilogue: +bb, relu, [BN], store rows r0+i0..+3, cols j0..j0+3 ----
    float4 bb4 = *(const float4*)&bb[j0];
    float bbv[4] = {bb4.x, bb4.y, bb4.z, bb4.w};
    float scv[4] = {0, 0, 0, 0}, shv[4] = {0, 0, 0, 0};
    if (HAS_BN) {
        float4 g4 = *(const float4*)&bng[j0];
        float4 b4 = *(const float4*)&bnb[j0];
        float4 m4 = *(const float4*)&bnm[j0];
        float4 v4 = *(const float4*)&bnv[j0];
        float gg[4] = {g4.x, g4.y, g4.z, g4.w};
        float bbn[4] = {b4.x, b4.y, b4.z, b4.w};
        float mm[4] = {m4.x, m4.y, m4.z, m4.w};
        float vv[4] = {v4.x, v4.y, v4.z, v4.w};
#pragma unroll
        for (int c = 0; c < 4; c++) {
            scv[c] = gg[c] * rsqrtf(vv[c] + 1e-5f);
            shv[c] = bbn[c] - mm[c] * scv[c];
        }
    }
#pragma unroll
    for (int di = 0; di < 4; di++) {
        int row = r0 + i0 + di;
        if (row >= n) break;
        float v[4];
#pragma unroll
        for (int dj = 0; dj < 4; dj++) {
            float tv = relu_f(acc2[di][dj] + bbv[dj]);
            if (HAS_BN) tv = fmaf(tv, scv[dj], shv[dj]);
            v[dj] = tv;
        }
        if (OUT_BF16) {
            ushort4 r;
            r.x = f2b(v[0]); r.y = f2b(v[1]); r.z = f2b(v[2]); r.w = f2b(v[3]);
            *(ushort4*)((ushort*)hout + (size_t)row * DD + j0) = r;
        } else {
            float4 r; r.x = v[0]; r.y = v[1]; r.z = v[2]; r.w = v[3];
            *(float4*)((float*)hout + (size_t)row * DD + j0) = r;
        }
    }
}

// ---------------- pooling: one block per graph, zero atomics ----------------
__global__ __launch_bounds__(256) void pool_kernel(
    const float* __restrict__ h, const int* __restrict__ gstart,
    float* __restrict__ pmean, float* __restrict__ pmax) {
    __shared__ float ssum[4][DD];
    __shared__ float smax[4][DD];
    int g = blockIdx.x;
    int lane = threadIdx.x & 63;
    int wave = threadIdx.x >> 6;
    int s = gstart[g], e = gstart[g + 1];
    float sum = 0.0f, mx = 0.0f;  // layer-2 out is post-ReLU >= 0; 0 == empty-graph guard
    for (int i = s + wave; i < e; i += 4) {
        float v = h[(size_t)i * DD + lane];
        sum += v;
        mx = fmaxf(mx, v);
    }
    ssum[wave][lane] = sum;
    smax[wave][lane] = mx;
    __syncthreads();
    if (wave == 0) {
        sum = ssum[0][lane] + ssum[1][lane] + ssum[2][lane] + ssum[3][lane];
        mx = fmaxf(fmaxf(smax[0][lane], smax[1][lane]),
                   fmaxf(smax[2][lane], smax[3][lane]));
        float cnt = fmaxf((float)(e - s), 1.0f);
        pmean[g * DD + lane] = sum / cnt;
        pmax[g * DD + lane] = mx;
    }
}

// ---------------- head: MLP + log_softmax, one 64-thread block per graph ----
__global__ __launch_bounds__(64) void head_kernel(
    const float* __restrict__ pmean, const float* __restrict__ pmax,
    const float* __restrict__ wp1, const float* __restrict__ bp1,
    const float* __restrict__ wp2, const float* __restrict__ bp2,
    float* __restrict__ out) {
    __shared__ float gx[2 * DD];
    int g = blockIdx.x;
    int lane = threadIdx.x;
    gx[lane] = pmean[g * DD + lane];
    gx[DD + lane] = pmax[g * DD + lane];
    __syncthreads();
    float t = bp1[lane];
    for (int k = 0; k < 2 * DD; k++) t = fmaf(gx[k], wp1[k * DD + lane], t);
    float p0 = t * wp2[lane * 2 + 0];
    float p1 = t * wp2[lane * 2 + 1];
    for (int o = 32; o > 0; o >>= 1) {
        p0 += __shfl_down(p0, o);
        p1 += __shfl_down(p1, o);
    }
    if (lane == 0) {
        p0 += bp2[0];
        p1 += bp2[1];
        float m = fmaxf(p0, p1);
        float lse = m + logf(expf(p0 - m) + expf(p1 - m));
        out[g * 2 + 0] = p0 - lse;
        out[g * 2 + 1] = p1 - lse;
    }
}

// ---------------- launch ----------------
extern "C" void kernel_launch(void* const* d_in, const int* in_sizes, int n_in,
                              void* d_out, int out_size, void* d_ws, size_t ws_size,
                              hipStream_t stream) {
    const float* x     = (const float*)d_in[0];
    const int*   ei    = (const int*)d_in[1];
    const int*   batch = (const int*)d_in[2];
    const float* w0a = (const float*)d_in[3];  const float* b0a = (const float*)d_in[4];
    const float* w0b = (const float*)d_in[5];  const float* b0b = (const float*)d_in[6];
    const float* w1a = (const float*)d_in[7];  const float* b1a = (const float*)d_in[8];
    const float* w1b = (const float*)d_in[9];  const float* b1b = (const float*)d_in[10];
    const float* w2a = (const float*)d_in[11]; const float* b2a = (const float*)d_in[12];
    const float* w2b = (const float*)d_in[13]; const float* b2b = (const float*)d_in[14];
    const float* bn0g = (const float*)d_in[15]; const float* bn0b = (const float*)d_in[16];
    const float* bn0m = (const float*)d_in[17]; const float* bn0v = (const float*)d_in[18];
    const float* bn1g = (const float*)d_in[19]; const float* bn1b = (const float*)d_in[20];
    const float* bn1m = (const float*)d_in[21]; const float* bn1v = (const float*)d_in[22];
    const float* wp1 = (const float*)d_in[23]; const float* bp1 = (const float*)d_in[24];
    const float* wp2 = (const float*)d_in[25]; const float* bp2 = (const float*)d_in[26];
    float* out = (float*)d_out;

    char* p = (char*)d_ws;
    auto take = [&](size_t bytes) {
        char* r = p;
        p += (bytes + 255) & ~(size_t)255;
        return r;
    };
    int* bhist   = (int*)take(NBUCK * sizeof(int));
    int* boffs   = (int*)take((NBUCK + 1) * sizeof(int));
    int* bcursor = (int*)take(NBUCK * sizeof(int));
    int* epack   = (int*)take(EE * sizeof(int));
    int* srcs    = (int*)take(EE * sizeof(int));
    int* off     = (int*)take((NN + 1) * sizeof(int));
    int* gstart  = (int*)take((GG + 1) * sizeof(int));
    ushort* xb   = (ushort*)take((size_t)NN * DD * sizeof(ushort));
    float* bufU  = (float*)take((size_t)NN * DD * sizeof(float));
    ushort* hA   = (ushort*)take((size_t)NN * DD * sizeof(ushort));
    ushort* hB   = (ushort*)take((size_t)NN * DD * sizeof(ushort));
    float* hC    = (float*)take((size_t)NN * DD * sizeof(float));
    float* pmean = (float*)take(GG * DD * sizeof(float));
    float* pmax  = (float*)take(GG * DD * sizeof(float));

    // two-stage CSR build + graph bounds + x cast
    hipMemsetAsync(bhist, 0, NBUCK * sizeof(int), stream);
    bhist_kernel<<<(EE + 255) / 256, 256, 0, stream>>>(ei + EE, bhist, EE);
    bscan_kernel<<<1, 1024, 0, stream>>>(bhist, boffs, bcursor);
    bscatter_kernel<<<(EE + 255) / 256, 256, 0, stream>>>(ei, bcursor, epack, EE);
    refine_kernel<<<(NBUCK + 3) / 4, 256, 0, stream>>>(epack, boffs, srcs, off);
    bounds_kernel<<<(NN + 255) / 256, 256, 0, stream>>>(batch, gstart, NN);
    cast_kernel<<<(NN * DD / 4 + 255) / 256, 256, 0, stream>>>(x, xb);

    int agg_grid = (NN + 3) / 4;
    int mlp_grid = (NN + DD - 1) / DD;   // 1563 blocks of 64 nodes

    // layer 0
    agg_kernel<<<agg_grid, 256, 0, stream>>>(xb, bufU, off, srcs, NN);
    mlp_kernel<true, true><<<mlp_grid, 256, 0, stream>>>(bufU, hA, w0a, b0a, w0b, b0b,
                                                         bn0g, bn0b, bn0m, bn0v, NN);
    // layer 1
    agg_kernel<<<agg_grid, 256, 0, stream>>>(hA, bufU, off, srcs, NN);
    mlp_kernel<true, true><<<mlp_grid, 256, 0, stream>>>(bufU, hB, w1a, b1a, w1b, b1b,
                                                         bn1g, bn1b, bn1m, bn1v, NN);
    // layer 2 (fp32 out)
    agg_kernel<<<agg_grid, 256, 0, stream>>>(hB, bufU, off, srcs, NN);
    mlp_kernel<false, false><<<mlp_grid, 256, 0, stream>>>(bufU, hC, w2a, b2a, w2b, b2b,
                                                           nullptr, nullptr, nullptr, nullptr, NN);

    // pooling (fp32 in, no atomics) + head
    pool_kernel<<<GG, 256, 0, stream>>>(hC, gstart, pmean, pmax);
    head_kernel<<<GG, 64, 0, stream>>>(pmean, pmax, wp1, bp1, wp2, bp2, out);
}

// Round 11
// 342.606 us; speedup vs baseline: 1.7848x; 1.2114x over previous
//
#include <hip/hip_runtime.h>
#include <hip/hip_bf16.h>

#define NN 100000
#define EE 1250000
#define DD 64
#define GG 256
#define COARSE 1024
#define NC ((NN + COARSE - 1) / COARSE)     // 98 coarse buckets
#define CHUNK 2048
#define NCHUNK ((EE + CHUNK - 1) / CHUNK)   // 611

static __device__ __forceinline__ float relu_f(float x) { return fmaxf(x, 0.0f); }

static __device__ __forceinline__ float b2f(ushort u) {
    return __uint_as_float(((unsigned int)u) << 16);
}
static __device__ __forceinline__ ushort f2b(float f) {
    __hip_bfloat16 h = __float2bfloat16(f);  // RNE
    return *(ushort*)&h;
}

// ---------------- coarse histogram (LDS pre-aggregated) ----------------
__global__ __launch_bounds__(256) void hist2_kernel(const int* __restrict__ dst,
                                                    int* __restrict__ ghist, int E) {
    __shared__ int h[NC];
    int t = threadIdx.x;
    if (t < NC) h[t] = 0;
    __syncthreads();
    for (int e = blockIdx.x * blockDim.x + t; e < E; e += gridDim.x * blockDim.x)
        atomicAdd(&h[dst[e] >> 10], 1);
    __syncthreads();
    if (t < NC && h[t]) atomicAdd(&ghist[t], h[t]);
}

// tiny scan over NC=98
__global__ void scan2_kernel(const int* __restrict__ ghist, int* __restrict__ coffs,
                             int* __restrict__ gcursor) {
    if (threadIdx.x == 0) {
        int run = 0;
        for (int b = 0; b < NC; b++) {
            coffs[b] = run;
            gcursor[b] = run;
            run += ghist[b];
        }
        coffs[NC] = run;
    }
}

// ---------------- LDS-binned scatter: coalesced bucket-run writes ----------------
// pack = src (17b) | dstLocal (10b) << 17
__global__ __launch_bounds__(256) void bin_kernel(
    const int* __restrict__ ei, int* __restrict__ gcursor, int* __restrict__ epack, int E) {
    __shared__ int hist[NC];
    __shared__ int base[NC];
    __shared__ int lpre[NC];
    __shared__ int scnt;
    __shared__ int lbuf[CHUNK];
    __shared__ int lobuf[CHUNK];
    int t = threadIdx.x;
    for (int c = blockIdx.x; c < NCHUNK; c += gridDim.x) {
        int e0 = c * CHUNK;
        if (t < NC) hist[t] = 0;
        __syncthreads();
        int myb[8], myloc[8], mypack[8];
#pragma unroll
        for (int q = 0; q < 8; q++) {
            int e = e0 + q * 256 + t;
            if (e < E) {
                int d = ei[E + e];
                int s = ei[e];
                int b = d >> 10;
                myb[q] = b;
                mypack[q] = s | ((d & (COARSE - 1)) << 17);
                myloc[q] = atomicAdd(&hist[b], 1);
            } else myb[q] = -1;
        }
        __syncthreads();
        if (t < NC) base[t] = hist[t] ? atomicAdd(&gcursor[t], hist[t]) : 0;
        if (t == 0) {
            int run = 0;
            for (int b = 0; b < NC; b++) { lpre[b] = run; run += hist[b]; }
            scnt = run;
        }
        __syncthreads();
#pragma unroll
        for (int q = 0; q < 8; q++) {
            if (myb[q] >= 0) {
                int p = lpre[myb[q]] + myloc[q];
                lbuf[p] = mypack[q];
                lobuf[p] = base[myb[q]] + myloc[q];
            }
        }
        __syncthreads();
        int cnt = scnt;
#pragma unroll
        for (int q = 0; q < 8; q++) {
            int p = q * 256 + t;
            if (p < cnt) epack[lobuf[p]] = lbuf[p];   // consecutive p -> consecutive dest
        }
        __syncthreads();
    }
}

// ---------------- per-coarse-bucket exact CSR build (block-private window) ------
__global__ __launch_bounds__(256) void csr2_kernel(
    const int* __restrict__ epack, const int* __restrict__ coffs,
    int* __restrict__ srcs, int* __restrict__ off) {
    __shared__ int hist[COARSE];   // counts -> then cursors
    __shared__ int tmp[256];
    int b = blockIdx.x;
    int t = threadIdx.x;
    int c0 = coffs[b], c1 = coffs[b + 1];
    int nbase = b * COARSE;
#pragma unroll
    for (int j = 0; j < 4; j++) hist[t * 4 + j] = 0;
    __syncthreads();
    for (int e = c0 + t; e < c1; e += 256)
        atomicAdd(&hist[epack[e] >> 17], 1);
    __syncthreads();
    // block scan of 1024 (4 per thread)
    int h0 = hist[t * 4], h1 = hist[t * 4 + 1], h2 = hist[t * 4 + 2], h3 = hist[t * 4 + 3];
    int s4 = h0 + h1 + h2 + h3;
    tmp[t] = s4;
    __syncthreads();
    for (int d = 1; d < 256; d <<= 1) {
        int v = (t >= d) ? tmp[t - d] : 0;
        __syncthreads();
        tmp[t] += v;
        __syncthreads();
    }
    int run = tmp[t] - s4;
    int pre0 = run; run += h0;
    int pre1 = run; run += h1;
    int pre2 = run; run += h2;
    int pre3 = run;
    // off + cursor init
    int pres[4] = {pre0, pre1, pre2, pre3};
#pragma unroll
    for (int j = 0; j < 4; j++) {
        int node = nbase + t * 4 + j;
        if (node < NN) off[node] = c0 + pres[j];
        hist[t * 4 + j] = pres[j];   // reuse as cursor
    }
    if (b == NC - 1 && t == 0) off[NN] = c1;
    __syncthreads();
    for (int e = c0 + t; e < c1; e += 256) {
        int p = epack[e];
        int pos = c0 + atomicAdd(&hist[p >> 17], 1);
        srcs[pos] = p & 0x1FFFF;
    }
}

// graph boundaries from sorted batch
__global__ void bounds_kernel(const int* __restrict__ batch, int* __restrict__ gstart, int n) {
    int i = blockIdx.x * blockDim.x + threadIdx.x;
    if (i >= n) return;
    int b = batch[i];
    int prev = (i == 0) ? -1 : batch[i - 1];
    for (int g = prev + 1; g <= b; g++) gstart[g] = i;
    if (i == n - 1) {
        for (int g = b + 1; g <= GG; g++) gstart[g] = n;
    }
}

// fp32 -> bf16 cast of x (once)
__global__ __launch_bounds__(256) void cast_kernel(const float* __restrict__ x,
                                                   ushort* __restrict__ xb) {
    size_t i = ((size_t)blockIdx.x * blockDim.x + threadIdx.x) * 4;
    if (i >= (size_t)NN * DD) return;
    float4 v = *(const float4*)(x + i);
    ushort4 r;
    r.x = f2b(v.x); r.y = f2b(v.y); r.z = f2b(v.z); r.w = f2b(v.w);
    *(ushort4*)(xb + i) = r;
}

// ---------------- aggregation: wave per node, bf16 gather, 8-deep unroll ------
__global__ __launch_bounds__(256) void agg_kernel(
    const ushort* __restrict__ xb, float* __restrict__ u,
    const int* __restrict__ off, const int* __restrict__ srcs, int n) {
    int node = blockIdx.x * 4 + (threadIdx.x >> 6);
    int lane = threadIdx.x & 63;
    if (node >= n) return;
    int o = off[node];
    int oe = off[node + 1];
    float a0 = b2f(xb[(size_t)node * DD + lane]);   // self
    float a1 = 0.0f, a2 = 0.0f, a3 = 0.0f, a4 = 0.0f, a5 = 0.0f, a6 = 0.0f, a7 = 0.0f;
    int j = o;
    for (; j + 8 <= oe; j += 8) {
        int s0 = srcs[j + 0], s1 = srcs[j + 1], s2 = srcs[j + 2], s3 = srcs[j + 3];
        int s4 = srcs[j + 4], s5 = srcs[j + 5], s6 = srcs[j + 6], s7 = srcs[j + 7];
        ushort v0 = xb[(size_t)s0 * DD + lane];
        ushort v1 = xb[(size_t)s1 * DD + lane];
        ushort v2 = xb[(size_t)s2 * DD + lane];
        ushort v3 = xb[(size_t)s3 * DD + lane];
        ushort v4 = xb[(size_t)s4 * DD + lane];
        ushort v5 = xb[(size_t)s5 * DD + lane];
        ushort v6 = xb[(size_t)s6 * DD + lane];
        ushort v7 = xb[(size_t)s7 * DD + lane];
        a0 += b2f(v0); a1 += b2f(v1); a2 += b2f(v2); a3 += b2f(v3);
        a4 += b2f(v4); a5 += b2f(v5); a6 += b2f(v6); a7 += b2f(v7);
    }
    for (; j + 4 <= oe; j += 4) {
        int s0 = srcs[j + 0], s1 = srcs[j + 1], s2 = srcs[j + 2], s3 = srcs[j + 3];
        ushort v0 = xb[(size_t)s0 * DD + lane];
        ushort v1 = xb[(size_t)s1 * DD + lane];
        ushort v2 = xb[(size_t)s2 * DD + lane];
        ushort v3 = xb[(size_t)s3 * DD + lane];
        a0 += b2f(v0); a1 += b2f(v1); a2 += b2f(v2); a3 += b2f(v3);
    }
    for (; j < oe; j++) a0 += b2f(xb[(size_t)srcs[j] * DD + lane]);
    u[(size_t)node * DD + lane] = ((a0 + a1) + (a2 + a3)) + ((a4 + a5) + (a6 + a7));
}

// ---------------- per-layer: block-tiled fp32 GEMM MLP (round-10 proven) ----
template <bool HAS_BN, bool OUT_BF16>
__global__ __launch_bounds__(256) void mlp_kernel(
    const float* __restrict__ u, void* __restrict__ hout,
    const float* __restrict__ wa, const float* __restrict__ ba,
    const float* __restrict__ wb, const float* __restrict__ bb,
    const float* __restrict__ bng, const float* __restrict__ bnb,
    const float* __restrict__ bnm, const float* __restrict__ bnv, int n) {
    __shared__ float At[DD][68];   // A^T: At[k][i], 68-pad keeps rows 16B-aligned
    __shared__ float Wt[DD * DD];  // W[k][j] row-major
    int t = threadIdx.x;
    int r0 = blockIdx.x * DD;
    int tx = t & 15, ty = t >> 4;
    int i0 = tx * 4, j0 = ty * 4;

    {
        int ii = t >> 2;
        int cb = (t & 3) * 16;
        int row = r0 + ii;
        if (row < n) {
            const float4* ur = (const float4*)(u + (size_t)row * DD + cb);
            float4 v0 = ur[0], v1 = ur[1], v2 = ur[2], v3 = ur[3];
            At[cb + 0][ii] = v0.x;  At[cb + 1][ii] = v0.y;
            At[cb + 2][ii] = v0.z;  At[cb + 3][ii] = v0.w;
            At[cb + 4][ii] = v1.x;  At[cb + 5][ii] = v1.y;
            At[cb + 6][ii] = v1.z;  At[cb + 7][ii] = v1.w;
            At[cb + 8][ii] = v2.x;  At[cb + 9][ii] = v2.y;
            At[cb + 10][ii] = v2.z; At[cb + 11][ii] = v2.w;
            At[cb + 12][ii] = v3.x; At[cb + 13][ii] = v3.y;
            At[cb + 14][ii] = v3.z; At[cb + 15][ii] = v3.w;
        } else {
#pragma unroll
            for (int q = 0; q < 16; q++) At[cb + q][ii] = 0.0f;
        }
#pragma unroll
        for (int rep = 0; rep < 4; rep++) {
            int idx = rep * 1024 + t * 4;
            *(float4*)&Wt[idx] = *(const float4*)&wa[idx];
        }
    }
    __syncthreads();

    float acc[4][4];
#pragma unroll
    for (int a = 0; a < 4; a++)
#pragma unroll
        for (int b = 0; b < 4; b++) acc[a][b] = 0.0f;
#pragma unroll 4
    for (int k = 0; k < DD; k++) {
        float4 av = *(const float4*)&At[k][i0];
        float4 wv = *(const float4*)&Wt[k * DD + j0];
        float aa[4] = {av.x, av.y, av.z, av.w};
        float ww[4] = {wv.x, wv.y, wv.z, wv.w};
#pragma unroll
        for (int di = 0; di < 4; di++)
#pragma unroll
            for (int dj = 0; dj < 4; dj++)
                acc[di][dj] = fmaf(aa[di], ww[dj], acc[di][dj]);
    }
    float4 ba4 = *(const float4*)&ba[j0];
    float bav[4] = {ba4.x, ba4.y, ba4.z, ba4.w};
    __syncthreads();

#pragma unroll
    for (int dj = 0; dj < 4; dj++) {
        float4 w;
        w.x = relu_f(acc[0][dj] + bav[dj]);
        w.y = relu_f(acc[1][dj] + bav[dj]);
        w.z = relu_f(acc[2][dj] + bav[dj]);
        w.w = relu_f(acc[3][dj] + bav[dj]);
        *(float4*)&At[j0 + dj][i0] = w;
    }
#pragma unroll
    for (int rep = 0; rep < 4; rep++) {
        int idx = rep * 1024 + t * 4;
        *(float4*)&Wt[idx] = *(const float4*)&wb[idx];
    }
    __syncthreads();

    float acc2[4][4];
#pragma unroll
    for (int a = 0; a < 4; a++)
#pragma unroll
        for (int b = 0; b < 4; b++) acc2[a][b] = 0.0f;
#pragma unroll 4
    for (int k = 0; k < DD; k++) {
        float4 av = *(const float4*)&At[k][i0];
        float4 wv = *(const float4*)&Wt[k * DD + j0];
        float aa[4] = {av.x, av.y, av.z, av.w};
        float ww[4] = {wv.x, wv.y, wv.z, wv.w};
#pragma unroll
        for (int di = 0; di < 4; di++)
#pragma unroll
            for (int dj = 0; dj < 4; dj++)
                acc2[di][dj] = fmaf(aa[di], ww[dj], acc2[di][dj]);
    }

    float4 bb4 = *(const float4*)&bb[j0];
    float bbv[4] = {bb4.x, bb4.y, bb4.z, bb4.w};
    float scv[4] = {0, 0, 0, 0}, shv[4] = {0, 0, 0, 0};
    if (HAS_BN) {
        float4 g4 = *(const float4*)&bng[j0];
        float4 b4 = *(const float4*)&bnb[j0];
        float4 m4 = *(const float4*)&bnm[j0];
        float4 v4 = *(const float4*)&bnv[j0];
        float gg[4] = {g4.x, g4.y, g4.z, g4.w};
        float bbn[4] = {b4.x, b4.y, b4.z, b4.w};
        float mm[4] = {m4.x, m4.y, m4.z, m4.w};
        float vv[4] = {v4.x, v4.y, v4.z, v4.w};
#pragma unroll
        for (int c = 0; c < 4; c++) {
            scv[c] = gg[c] * rsqrtf(vv[c] + 1e-5f);
            shv[c] = bbn[c] - mm[c] * scv[c];
        }
    }
#pragma unroll
    for (int di = 0; di < 4; di++) {
        int row = r0 + i0 + di;
        if (row >= n) break;
        float v[4];
#pragma unroll
        for (int dj = 0; dj < 4; dj++) {
            float tv = relu_f(acc2[di][dj] + bbv[dj]);
            if (HAS_BN) tv = fmaf(tv, scv[dj], shv[dj]);
            v[dj] = tv;
        }
        if (OUT_BF16) {
            ushort4 r;
            r.x = f2b(v[0]); r.y = f2b(v[1]); r.z = f2b(v[2]); r.w = f2b(v[3]);
            *(ushort4*)((ushort*)hout + (size_t)row * DD + j0) = r;
        } else {
            float4 r; r.x = v[0]; r.y = v[1]; r.z = v[2]; r.w = v[3];
            *(float4*)((float*)hout + (size_t)row * DD + j0) = r;
        }
    }
}

// ---------------- pooling: one block per graph, zero atomics ----------------
__global__ __launch_bounds__(256) void pool_kernel(
    const float* __restrict__ h, const int* __restrict__ gstart,
    float* __restrict__ pmean, float* __restrict__ pmax) {
    __shared__ float ssum[4][DD];
    __shared__ float smax[4][DD];
    int g = blockIdx.x;
    int lane = threadIdx.x & 63;
    int wave = threadIdx.x >> 6;
    int s = gstart[g], e = gstart[g + 1];
    float sum = 0.0f, mx = 0.0f;  // layer-2 out is post-ReLU >= 0; 0 == empty-graph guard
    for (int i = s + wave; i < e; i += 4) {
        float v = h[(size_t)i * DD + lane];
        sum += v;
        mx = fmaxf(mx, v);
    }
    ssum[wave][lane] = sum;
    smax[wave][lane] = mx;
    __syncthreads();
    if (wave == 0) {
        sum = ssum[0][lane] + ssum[1][lane] + ssum[2][lane] + ssum[3][lane];
        mx = fmaxf(fmaxf(smax[0][lane], smax[1][lane]),
                   fmaxf(smax[2][lane], smax[3][lane]));
        float cnt = fmaxf((float)(e - s), 1.0f);
        pmean[g * DD + lane] = sum / cnt;
        pmax[g * DD + lane] = mx;
    }
}

// ---------------- head: MLP + log_softmax, one 64-thread block per graph ----
__global__ __launch_bounds__(64) void head_kernel(
    const float* __restrict__ pmean, const float* __restrict__ pmax,
    const float* __restrict__ wp1, const float* __restrict__ bp1,
    const float* __restrict__ wp2, const float* __restrict__ bp2,
    float* __restrict__ out) {
    __shared__ float gx[2 * DD];
    int g = blockIdx.x;
    int lane = threadIdx.x;
    gx[lane] = pmean[g * DD + lane];
    gx[DD + lane] = pmax[g * DD + lane];
    __syncthreads();
    float t = bp1[lane];
    for (int k = 0; k < 2 * DD; k++) t = fmaf(gx[k], wp1[k * DD + lane], t);
    float p0 = t * wp2[lane * 2 + 0];
    float p1 = t * wp2[lane * 2 + 1];
    for (int o = 32; o > 0; o >>= 1) {
        p0 += __shfl_down(p0, o);
        p1 += __shfl_down(p1, o);
    }
    if (lane == 0) {
        p0 += bp2[0];
        p1 += bp2[1];
        float m = fmaxf(p0, p1);
        float lse = m + logf(expf(p0 - m) + expf(p1 - m));
        out[g * 2 + 0] = p0 - lse;
        out[g * 2 + 1] = p1 - lse;
    }
}

// ---------------- launch ----------------
extern "C" void kernel_launch(void* const* d_in, const int* in_sizes, int n_in,
                              void* d_out, int out_size, void* d_ws, size_t ws_size,
                              hipStream_t stream) {
    const float* x     = (const float*)d_in[0];
    const int*   ei    = (const int*)d_in[1];
    const int*   batch = (const int*)d_in[2];
    const float* w0a = (const float*)d_in[3];  const float* b0a = (const float*)d_in[4];
    const float* w0b = (const float*)d_in[5];  const float* b0b = (const float*)d_in[6];
    const float* w1a = (const float*)d_in[7];  const float* b1a = (const float*)d_in[8];
    const float* w1b = (const float*)d_in[9];  const float* b1b = (const float*)d_in[10];
    const float* w2a = (const float*)d_in[11]; const float* b2a = (const float*)d_in[12];
    const float* w2b = (const float*)d_in[13]; const float* b2b = (const float*)d_in[14];
    const float* bn0g = (const float*)d_in[15]; const float* bn0b = (const float*)d_in[16];
    const float* bn0m = (const float*)d_in[17]; const float* bn0v = (const float*)d_in[18];
    const float* bn1g = (const float*)d_in[19]; const float* bn1b = (const float*)d_in[20];
    const float* bn1m = (const float*)d_in[21]; const float* bn1v = (const float*)d_in[22];
    const float* wp1 = (const float*)d_in[23]; const float* bp1 = (const float*)d_in[24];
    const float* wp2 = (const float*)d_in[25]; const float* bp2 = (const float*)d_in[26];
    float* out = (float*)d_out;

    char* p = (char*)d_ws;
    auto take = [&](size_t bytes) {
        char* r = p;
        p += (bytes + 255) & ~(size_t)255;
        return r;
    };
    int* ghist   = (int*)take(NC * sizeof(int));
    int* coffs   = (int*)take((NC + 1) * sizeof(int));
    int* gcursor = (int*)take(NC * sizeof(int));
    int* epack   = (int*)take(EE * sizeof(int));
    int* srcs    = (int*)take(EE * sizeof(int));
    int* off     = (int*)take((NN + 1) * sizeof(int));
    int* gstart  = (int*)take((GG + 1) * sizeof(int));
    ushort* xb   = (ushort*)take((size_t)NN * DD * sizeof(ushort));
    float* bufU  = (float*)take((size_t)NN * DD * sizeof(float));
    ushort* hA   = (ushort*)take((size_t)NN * DD * sizeof(ushort));
    ushort* hB   = (ushort*)take((size_t)NN * DD * sizeof(ushort));
    float* hC    = (float*)take((size_t)NN * DD * sizeof(float));
    float* pmean = (float*)take(GG * DD * sizeof(float));
    float* pmax  = (float*)take(GG * DD * sizeof(float));

    // CSR build: coarse hist -> scan -> LDS-binned scatter -> per-bucket CSR
    hipMemsetAsync(ghist, 0, NC * sizeof(int), stream);
    hist2_kernel<<<512, 256, 0, stream>>>(ei + EE, ghist, EE);
    scan2_kernel<<<1, 64, 0, stream>>>(ghist, coffs, gcursor);
    bin_kernel<<<512, 256, 0, stream>>>(ei, gcursor, epack, EE);
    csr2_kernel<<<NC, 256, 0, stream>>>(epack, coffs, srcs, off);
    bounds_kernel<<<(NN + 255) / 256, 256, 0, stream>>>(batch, gstart, NN);
    cast_kernel<<<(NN * DD / 4 + 255) / 256, 256, 0, stream>>>(x, xb);

    int agg_grid = (NN + 3) / 4;
    int mlp_grid = (NN + DD - 1) / DD;   // 1563 blocks of 64 nodes

    // layer 0
    agg_kernel<<<agg_grid, 256, 0, stream>>>(xb, bufU, off, srcs, NN);
    mlp_kernel<true, true><<<mlp_grid, 256, 0, stream>>>(bufU, hA, w0a, b0a, w0b, b0b,
                                                         bn0g, bn0b, bn0m, bn0v, NN);
    // layer 1
    agg_kernel<<<agg_grid, 256, 0, stream>>>(hA, bufU, off, srcs, NN);
    mlp_kernel<true, true><<<mlp_grid, 256, 0, stream>>>(bufU, hB, w1a, b1a, w1b, b1b,
                                                         bn1g, bn1b, bn1m, bn1v, NN);
    // layer 2 (fp32 out)
    agg_kernel<<<agg_grid, 256, 0, stream>>>(hB, bufU, off, srcs, NN);
    mlp_kernel<false, false><<<mlp_grid, 256, 0, stream>>>(bufU, hC, w2a, b2a, w2b, b2b,
                                                           nullptr, nullptr, nullptr, nullptr, NN);

    // pooling (fp32 in, no atomics) + head
    pool_kernel<<<GG, 256, 0, stream>>>(hC, gstart, pmean, pmax);
    head_kernel<<<GG, 64, 0, stream>>>(pmean, pmax, wp1, bp1, wp2, bp2, out);
}